// Round 1
// baseline (778.509 us; speedup 1.0000x reference)
//
#include <hip/hip_runtime.h>
#include <stdint.h>

#define T_STEPS 500
#define NBATCH  128
#define NIN     784
#define KPAD    800
#define NH      1024
#define NSL     102
#define DECAY   0.8807970779778823f

typedef __attribute__((ext_vector_type(8))) short short8;
typedef __attribute__((ext_vector_type(8))) unsigned short ushort8;
typedef __attribute__((ext_vector_type(4))) float f32x4;

static __device__ __forceinline__ unsigned short f2bf(float f) {
  union { float f; unsigned u; } v; v.f = f;
  unsigned r = (v.u + 0x7FFFu + ((v.u >> 16) & 1u)) >> 16;
  return (unsigned short)r;
}
static __device__ __forceinline__ float bf2f(unsigned short s) {
  union { unsigned u; float f; } v; v.u = ((unsigned)s) << 16;
  return v.f;
}

// ---------------- prep: fc1 -> bf16, transposed [NH][KPAD], K zero-padded ----
__global__ __launch_bounds__(256) void prep_kernel(
    const float* __restrict__ fc1, unsigned short* __restrict__ fc1T,
    float* __restrict__ out_last) {
  int idx = blockIdx.x * 256 + threadIdx.x;
  if (idx < NH * KPAD) {
    int n = idx / KPAD, k = idx - n * KPAD;
    float v = (k < NIN) ? fc1[(size_t)k * NH + n] : 0.0f;
    fc1T[idx] = f2bf(v);
  }
  if (idx == 0) *out_last = 500.0f;  // second tuple output: T
}

// ---------------- GEMM: cur_in[64000][1024] = X @ fc1  (bf16 out) -----------
__global__ __launch_bounds__(256) void gemm_kernel(
    const float* __restrict__ x, const unsigned short* __restrict__ fc1T,
    unsigned short* __restrict__ curq) {
  __shared__ __align__(16) unsigned short Alds[128 * 40];  // row stride 40 (pad)
  __shared__ __align__(16) unsigned short Blds[128 * 40];  // B^T: [n][k]

  const int tid = threadIdx.x;
  const int m0 = blockIdx.y * 128, n0 = blockIdx.x * 128;
  const int lane = tid & 63, wave = tid >> 6;
  const int wr = (wave >> 1) * 64, wc = (wave & 1) * 64;
  const int l16 = lane & 15, q = lane >> 4;

  const int r = tid >> 1;          // staging row 0..127
  const int kofs = (tid & 1) * 16; // k sub-half 0/16

  f32x4 acc[4][4];
  const f32x4 zero4 = {0.0f, 0.0f, 0.0f, 0.0f};
#pragma unroll
  for (int i = 0; i < 4; ++i)
#pragma unroll
    for (int j = 0; j < 4; ++j) acc[i][j] = zero4;

  for (int k0 = 0; k0 < KPAD; k0 += 32) {
    // --- stage A: X fp32 -> bf16, 128x32 tile
    ushort8 va0, va1;
    if (k0 + kofs < NIN) {  // uniform per half-tile: 784 is a multiple of 16
      const float4* src = (const float4*)(x + (size_t)(m0 + r) * NIN + k0 + kofs);
      float4 f0 = src[0], f1 = src[1], f2 = src[2], f3 = src[3];
      va0[0]=f2bf(f0.x); va0[1]=f2bf(f0.y); va0[2]=f2bf(f0.z); va0[3]=f2bf(f0.w);
      va0[4]=f2bf(f1.x); va0[5]=f2bf(f1.y); va0[6]=f2bf(f1.z); va0[7]=f2bf(f1.w);
      va1[0]=f2bf(f2.x); va1[1]=f2bf(f2.y); va1[2]=f2bf(f2.z); va1[3]=f2bf(f2.w);
      va1[4]=f2bf(f3.x); va1[5]=f2bf(f3.y); va1[6]=f2bf(f3.z); va1[7]=f2bf(f3.w);
    } else {
#pragma unroll
      for (int v = 0; v < 8; ++v) { va0[v] = 0; va1[v] = 0; }
    }
    *(ushort8*)&Alds[r * 40 + kofs]     = va0;
    *(ushort8*)&Alds[r * 40 + kofs + 8] = va1;

    // --- stage B: fc1T bf16 rows (already transposed & padded)
    const ushort8* bs = (const ushort8*)(fc1T + (size_t)(n0 + r) * KPAD + k0 + kofs);
    ushort8 vb0 = bs[0], vb1 = bs[1];
    *(ushort8*)&Blds[r * 40 + kofs]     = vb0;
    *(ushort8*)&Blds[r * 40 + kofs + 8] = vb1;

    __syncthreads();

    short8 av[4], bv[4];
#pragma unroll
    for (int i = 0; i < 4; ++i) {
      av[i] = *(const short8*)&Alds[(wr + i * 16 + l16) * 40 + q * 8];
      bv[i] = *(const short8*)&Blds[(wc + i * 16 + l16) * 40 + q * 8];
    }
#pragma unroll
    for (int i = 0; i < 4; ++i)
#pragma unroll
      for (int j = 0; j < 4; ++j)
        acc[i][j] = __builtin_amdgcn_mfma_f32_16x16x32_bf16(av[i], bv[j], acc[i][j], 0, 0, 0);

    __syncthreads();
  }

  // epilogue: C/D layout col=lane&15, row=q*4+reg
#pragma unroll
  for (int i = 0; i < 4; ++i)
#pragma unroll
    for (int j = 0; j < 4; ++j) {
      int row = m0 + wr + i * 16 + q * 4;
      int col = n0 + wc + j * 16 + l16;
#pragma unroll
      for (int rr = 0; rr < 4; ++rr)
        curq[(size_t)(row + rr) * NH + col] = f2bf(acc[i][j][rr]);
    }
}

// ---------------- scan: one block per batch; incremental delta-spike rsum ----
__global__ __launch_bounds__(256) void scan_kernel(
    const unsigned short* __restrict__ curq, const float* __restrict__ wrec,
    float* __restrict__ out) {
  const int b = blockIdx.x, tid = threadIdx.x;
  const int h0 = tid * 4;  // 4 hidden cols per thread

  __shared__ unsigned short lst[2][1024];  // delta lists (double buffered)
  __shared__ int cnt[2];

  unsigned lane = __builtin_amdgcn_mbcnt_hi(~0u, __builtin_amdgcn_mbcnt_lo(~0u, 0u));
  unsigned long long ltmask = (1ull << lane) - 1ull;

  float mem[4] = {0, 0, 0, 0}, rs[4] = {0, 0, 0, 0}, sp[4] = {0, 0, 0, 0};

  if (tid < 2) cnt[tid] = 0;
  __syncthreads();

  const size_t rowbase = (size_t)b * T_STEPS;

  for (int tb = 0; tb < T_STEPS; tb += 4) {
    // chunked row prefetch: amortize barrier vmcnt(0) drain over 4 steps
    ushort4 cv[4];
#pragma unroll
    for (int u = 0; u < 4; ++u)
      cv[u] = *(const ushort4*)&curq[(rowbase + tb + u) * NH + h0];

#pragma unroll
    for (int u = 0; u < 4; ++u) {
      const int t = tb + u;
      const int cur = t & 1, prv = cur ^ 1;
      if (tid == 0) cnt[cur] = 0;

      // apply spike-set delta from step t-1 to running recurrent sums
      const int n = cnt[prv];
      for (int i = 0; i < n; ++i) {
        unsigned e = lst[prv][i];
        int j = e & 1023;
        float s = (e & 0x8000u) ? 1.0f : -1.0f;
        const float4 w = *(const float4*)&wrec[(size_t)j * NH + h0];
        rs[0] += s * w.x; rs[1] += s * w.y; rs[2] += s * w.z; rs[3] += s * w.w;
      }

      // leaky integrate + fire
      float cin[4] = {bf2f(cv[u].x), bf2f(cv[u].y), bf2f(cv[u].z), bf2f(cv[u].w)};
      float ns[4];
#pragma unroll
      for (int c = 0; c < 4; ++c) {
        float cc = cin[c] + rs[c];
        mem[c] = mem[c] * (DECAY * (1.0f - sp[c])) + cc;
        ns[c] = (mem[c] >= 1.0f) ? 1.0f : 0.0f;
      }

      // output slice spk[:, :102]
      if (h0 < NSL) {
        float* o = out + (rowbase + t) * NSL + h0;
        o[0] = ns[0];
        if (h0 + 1 < NSL) o[1] = ns[1];
        if (h0 + 2 < NSL) o[2] = ns[2];
        if (h0 + 3 < NSL) o[3] = ns[3];
      }

      __syncthreads();  // cnt[cur]=0 visible; everyone done reading lst[prv]

      // build new delta list (ballot compaction; no-op in steady state)
#pragma unroll
      for (int c = 0; c < 4; ++c) {
        bool ch = (ns[c] != sp[c]);
        unsigned long long msk = __ballot(ch);
        if (msk) {  // wave-uniform
          int base = 0;
          if (lane == 0) base = atomicAdd(&cnt[cur], (int)__popcll(msk));
          base = __shfl(base, 0, 64);
          if (ch) {
            int pos = base + (int)__popcll(msk & ltmask);
            lst[cur][pos] =
                (unsigned short)((h0 + c) | (ns[c] > 0.5f ? 0x8000u : 0u));
          }
        }
        sp[c] = ns[c];
      }
      __syncthreads();  // lst[cur] complete for step t+1
    }
  }
}

extern "C" void kernel_launch(void* const* d_in, const int* in_sizes, int n_in,
                              void* d_out, int out_size, void* d_ws, size_t ws_size,
                              hipStream_t stream) {
  const float* x    = (const float*)d_in[0];  // [128][500][784] fp32
  const float* fc1  = (const float*)d_in[1];  // [784][1024] fp32
  const float* wrec = (const float*)d_in[2];  // [1024][1024] fp32
  float* out = (float*)d_out;                 // [128][500][102] + [T]

  unsigned short* fc1T = (unsigned short*)d_ws;                      // 1,638,400 B
  unsigned short* curq = (unsigned short*)((char*)d_ws + 1638400);   // 131,072,000 B

  prep_kernel<<<dim3((NH * KPAD + 255) / 256), 256, 0, stream>>>(fc1, fc1T,
                                                                 out + (out_size - 1));
  gemm_kernel<<<dim3(8, 500), 256, 0, stream>>>(x, fc1T, curq);
  scan_kernel<<<dim3(NBATCH), 256, 0, stream>>>(curq, wrec, out);
}